// Round 5
// baseline (265.201 us; speedup 1.0000x reference)
//
#include <hip/hip_runtime.h>

// ---------------- types / helpers ----------------
typedef float  f32x4   __attribute__((ext_vector_type(4)));
typedef float  f32x16  __attribute__((ext_vector_type(16)));
typedef __bf16 bf16x8  __attribute__((ext_vector_type(8)));
typedef __bf16 bf16x2  __attribute__((ext_vector_type(2)));
typedef short  short8v __attribute__((ext_vector_type(8)));
typedef unsigned uint4v __attribute__((ext_vector_type(4)));

__device__ __forceinline__ short f2bf(float f) {
  unsigned u = __float_as_uint(f);
  unsigned r = (u + 0x7FFFu + ((u >> 16) & 1u)) >> 16;  // RNE
  return (short)r;
}

__device__ __forceinline__ f32x4 mfma16(bf16x8 a, bf16x8 b, f32x4 c) {
  return __builtin_amdgcn_mfma_f32_16x16x32_bf16(a, b, c, 0, 0, 0);
}
__device__ __forceinline__ f32x16 mfma32(bf16x8 a, bf16x8 b, f32x16 c) {
  return __builtin_amdgcn_mfma_f32_32x32x16_bf16(a, b, c, 0, 0, 0);
}

// async global->LDS, 16B per lane. lds base must be wave-uniform; HW adds lane*16.
__device__ __forceinline__ void gload16(const void* g, void* l) {
  __builtin_amdgcn_global_load_lds(
      (const __attribute__((address_space(1))) unsigned int*)g,
      (__attribute__((address_space(3))) unsigned int*)l,
      16, 0, 0);
}

// ---------------- problem constants ----------------
// B=2, T1=T2=2048, D_MODEL=1024, N_HEAD=16, D_HEAD=64

// ---------------- conversion kernels ----------------
__global__ __launch_bounds__(256) void cvt_copy(const float* __restrict__ in,
                                                short* __restrict__ out, int n4) {
  int i = blockIdx.x * blockDim.x + threadIdx.x;
  int stride = gridDim.x * blockDim.x;
  for (; i < n4; i += stride) {
    float4 v = *(const float4*)&in[i * 4];
    short4 o;
    o.x = f2bf(v.x); o.y = f2bf(v.y); o.z = f2bf(v.z); o.w = f2bf(v.w);
    *(short4*)&out[i * 4] = o;
  }
}

// 4 weight matrices [1024][1024] f32 (row=k,col=n) -> bf16 [n][k], one launch.
__global__ __launch_bounds__(256) void cvt_transpose4(const float* __restrict__ W0,
                                                      const float* __restrict__ W1,
                                                      const float* __restrict__ W2,
                                                      const float* __restrict__ W3,
                                                      short* __restrict__ T0,
                                                      short* __restrict__ T1,
                                                      short* __restrict__ T2,
                                                      short* __restrict__ T3) {
  __shared__ short t_s[64][72];
  int z = blockIdx.z;
  const float* W = (z == 0) ? W0 : (z == 1) ? W1 : (z == 2) ? W2 : W3;
  short* Wt = (z == 0) ? T0 : (z == 1) ? T1 : (z == 2) ? T2 : T3;
  int k0 = blockIdx.y * 64, n0 = blockIdx.x * 64;
  int tid = threadIdx.x;
#pragma unroll
  for (int i = 0; i < 4; i++) {
    int idx = i * 256 + tid;
    int r = idx >> 4, cg = idx & 15;
    float4 v = *(const float4*)&W[(k0 + r) * 1024 + n0 + cg * 4];
    t_s[cg * 4 + 0][r] = f2bf(v.x);
    t_s[cg * 4 + 1][r] = f2bf(v.y);
    t_s[cg * 4 + 2][r] = f2bf(v.z);
    t_s[cg * 4 + 3][r] = f2bf(v.w);
  }
  __syncthreads();
#pragma unroll
  for (int i = 0; i < 2; i++) {
    int idx = i * 256 + tid;
    int r = idx >> 3, cg = idx & 7;
    short8v val = *(short8v*)&t_s[r][cg * 8];
    *(short8v*)&Wt[(n0 + r) * 1024 + k0 + cg * 8] = val;
  }
}

// ---------------- GEMM: C[4096][N] = A[4096][1024] @ Bt^T ----------------
// EPI 0: N=1024, bf16 scatter to [B,H,T,64]          (Q projection)
// EPI 2: N=1024, f32 out + b_out                      (final projection)
// EPI 3: N=2048, cols<1024 -> K [B,H,T,64]; cols>=1024 -> V^T [B,H,64,T]
template <int EPI>
__global__ __launch_bounds__(256, 4) void gemm_bf16(const short* __restrict__ A,
                                                    const short* __restrict__ Bt,
                                                    void* __restrict__ out,
                                                    void* __restrict__ out2,
                                                    const float* __restrict__ bout) {
  constexpr int KD = 1024;
  constexpr int NB = (EPI == 3) ? 32 : 16;  // N-tiles
  __shared__ short a_s[64][64];
  __shared__ short b_s[64][64];
  int tid = threadIdx.x, w = tid >> 6, lane = tid & 63;
  int g = lane >> 4, c16 = lane & 15;
  int hsw = c16 & 7;

  // XCD swizzle (bijective: grid % 8 == 0)
  int lin = blockIdx.x + NB * blockIdx.y;
  int wk = (lin & 7) * (NB * 8) + (lin >> 3);
  int c0 = (wk & (NB - 1)) * 64, r0 = (wk / NB) * 64;

  int wr = (w >> 1) * 32, wc = (w & 1) * 32;
  f32x4 acc[2][2] = {};

  for (int kt = 0; kt < KD / 64; ++kt) {
    int k0 = kt * 64;
    __syncthreads();
#pragma unroll
    for (int i = 0; i < 2; i++) {
      int cb = i * 256 + w * 64;
      int c = cb + lane;
      int row = c >> 3, kg = c & 7;
      int sw = (kg ^ (row & 7)) * 8;   // pre-swizzled source col
      gload16(A + (r0 + row) * KD + k0 + sw, (char*)a_s + cb * 16);
      gload16(Bt + (c0 + row) * KD + k0 + sw, (char*)b_s + cb * 16);
    }
    __syncthreads();
#pragma unroll
    for (int kk = 0; kk < 2; kk++) {
      bf16x8 af[2], bf[2];
      int sl0 = ((4 * kk + g) ^ hsw) * 8;
#pragma unroll
      for (int m = 0; m < 2; m++) af[m] = *(const bf16x8*)&a_s[wr + m * 16 + c16][sl0];
#pragma unroll
      for (int n = 0; n < 2; n++) bf[n] = *(const bf16x8*)&b_s[wc + n * 16 + c16][sl0];
#pragma unroll
      for (int m = 0; m < 2; m++)
#pragma unroll
        for (int n = 0; n < 2; n++) acc[m][n] = mfma16(af[m], bf[n], acc[m][n]);
    }
  }

#pragma unroll
  for (int m = 0; m < 2; m++)
#pragma unroll
    for (int n = 0; n < 2; n++)
#pragma unroll
      for (int r = 0; r < 4; r++) {
        int row = r0 + wr + m * 16 + g * 4 + r;  // C/D: row=(lane>>4)*4+reg
        int col = c0 + wc + n * 16 + c16;        //      col=lane&15
        float v = acc[m][n][r];
        int b = row >> 11, t = row & 2047;
        if (EPI == 2) {
          ((float*)out)[row * 1024 + col] = v + bout[col];
        } else if (EPI == 0) {
          int h = col >> 6, d = col & 63;
          ((short*)out)[(((b * 16 + h) * 2048) + t) * 64 + d] = f2bf(v);
        } else {  // EPI 3: merged K | V^T
          if (col < 1024) {
            int h = col >> 6, d = col & 63;
            ((short*)out)[(((b * 16 + h) * 2048) + t) * 64 + d] = f2bf(v);
          } else {
            int cv = col - 1024;
            int h = cv >> 6, d = cv & 63;
            ((short*)out2)[(((b * 16 + h) * 64) + d) * 2048 + t] = f2bf(v);
          }
        }
      }
}

// ---------------- flash attention v4 ----------------
// 4 waves x 32 q-rows (QBLK=128), KVBLK=64, 32x32x16 MFMA, swapped QK^T.
// P stays in registers: bf16-pack + __shfl_xor(32) half-exchange (T12 analog).
// K/V double-buffered in 32KB LDS, counted vmcnt, setprio, XCD swizzle.
//
// 32x32 C-layout (m74/m101): col = lane&31, row = (reg&3) + 8*(reg>>2) + 4*(lane>>5).
// Swapped QK: D[k][q]: q = lane&31 (fixed per lane), k = row formula -> softmax
// is lane-local. PV A-frag needs P[q=lane&31][k = 16m+8hi+j]:
//   j=0..3 live in half hi=0's regs r=4*(2(m&1)+hi_req)+j, j=4..7 in half 1's same
//   regs; with pk[i] = pack(S[2i],S[2i+1]) the exchange is one shfl_xor(32) pair
//   per (tile, m&1), payload chosen per half.
__global__ __launch_bounds__(256, 4) void flash_attn(const short* __restrict__ Qg,
                                                     const short* __restrict__ Kg,
                                                     const short* __restrict__ Vtg,
                                                     const float* __restrict__ bias,
                                                     short* __restrict__ Og) {
  __shared__ short k_s[2][64][64];   // [buf][k][d]  16B-slot XOR-swizzled by row&7
  __shared__ short v_s[2][64][64];   // [buf][d][k]  16B-slot XOR-swizzled by row&7

  int tid = threadIdx.x, w = tid >> 6, lane = tid & 63;
  int hi = lane >> 5, ll = lane & 31;
  int l7 = ll & 7;

  // XCD swizzle: 512 blocks -> 64-chunks per XCD
  int lin = blockIdx.x + 16 * (blockIdx.y + 16 * blockIdx.z);
  int wk = (lin & 7) * 64 + (lin >> 3);
  int qb = (wk & 15) * 128;
  int h = (wk >> 4) & 15;
  int b = wk >> 8;

  const short* Qh = Qg + (size_t)(b * 16 + h) * 2048 * 64;
  const short* Kh = Kg + (size_t)(b * 16 + h) * 2048 * 64;
  const short* Vh = Vtg + (size_t)(b * 16 + h) * 64 * 2048;

  const float C1 = 0.125f * 1.44269504f;                 // atten_scale * log2(e)
  const float C2 = exp2f(-(float)(h + 1)) * 1.44269504f; // head_scale * log2(e)

  int qrow = qb + w * 32 + ll;
  const float* bp = bias + (size_t)qrow * 2048 + 4 * hi;

  // ---- prologue: stage tile 0 (4 gload16/thread), Q B-frags to registers ----
#pragma unroll
  for (int i = 0; i < 2; i++) {
    int cb = i * 256 + w * 64;
    int c = cb + lane;
    int row = c >> 3, t8 = c & 7, sw = (t8 ^ (row & 7)) * 8;
    gload16(Kh + row * 64 + sw, (char*)&k_s[0][0][0] + cb * 16);
    gload16(Vh + row * 2048 + sw, (char*)&v_s[0][0][0] + cb * 16);
  }
  bf16x8 qf[4];
#pragma unroll
  for (int dm = 0; dm < 4; dm++)
    qf[dm] = *(const bf16x8*)(Qh + (size_t)qrow * 64 + dm * 16 + hi * 8);
  asm volatile("" ::: "memory");  // keep prologue VMEM oldest in the queue

  float l_run = 0.f;
  f32x16 o_acc[2] = {};  // [dt]: col d = dt*32+ll, row q = (r&3)+8*(r>>2)+4*hi

#pragma unroll 2
  for (int kt = 0; kt < 32; ++kt) {
    int cur = kt & 1;
    // bias: 8x float4 per lane; reg r of tile t <-> bv[t][r>>2][r&3]
    f32x4 bv[2][4];
#pragma unroll
    for (int t = 0; t < 2; t++)
#pragma unroll
      for (int u = 0; u < 4; u++)
        bv[t][u] = *(const f32x4*)(bp + kt * 64 + t * 32 + u * 8);

    if (kt < 31) {
      const short* Ks = Kh + (size_t)(kt + 1) * 64 * 64;
      const short* Vs = Vh + (kt + 1) * 64;
#pragma unroll
      for (int i = 0; i < 2; i++) {
        int cb = i * 256 + w * 64;
        int c = cb + lane;
        int row = c >> 3, t8 = c & 7, sw = (t8 ^ (row & 7)) * 8;
        gload16(Ks + row * 64 + sw, (char*)&k_s[cur ^ 1][0][0] + cb * 16);
        gload16(Vs + row * 2048 + sw, (char*)&v_s[cur ^ 1][0][0] + cb * 16);
      }
      // outstanding: [cur-stage 4 oldest][bias 8][next-stage 4] -> drain cur
      asm volatile("s_waitcnt vmcnt(12)" ::: "memory");
    } else {
      asm volatile("s_waitcnt vmcnt(8)" ::: "memory");  // [cur 4][bias 8]
    }
    __builtin_amdgcn_s_barrier();  // (a) cur buffer staged on all waves

    // ---- S[k][q]: A = K rows (LDS), B = Q cols (regs); 2 tiles x 4 mfma ----
    f32x16 sacc[2] = {};
    __builtin_amdgcn_s_setprio(1);
#pragma unroll
    for (int t = 0; t < 2; t++)
#pragma unroll
      for (int dm = 0; dm < 4; dm++) {
        const short* kr = &k_s[cur][t * 32 + ll][((2 * dm + hi) ^ l7) * 8];
        sacc[t] = mfma32(*(const bf16x8*)kr, qf[dm], sacc[t]);
      }
    __builtin_amdgcn_s_setprio(0);

    // ---- softmax numerator (exp2-domain, no max subtraction) + P pack ----
    float lp = 0.f;
    bf16x8 PA[4];
#pragma unroll
    for (int t = 0; t < 2; t++) {
      unsigned pk[8];
#pragma unroll
      for (int i = 0; i < 8; i++) {
        float p0 = exp2f(sacc[t][2 * i] * C1 + bv[t][i >> 1][2 * (i & 1)] * C2);
        float p1 = exp2f(sacc[t][2 * i + 1] * C1 + bv[t][i >> 1][2 * (i & 1) + 1] * C2);
        lp += p0 + p1;
        bf16x2 pp = {(__bf16)p0, (__bf16)p1};
        pk[i] = __builtin_bit_cast(unsigned, pp);
      }
#pragma unroll
      for (int a = 0; a < 2; a++) {
        unsigned y1 = hi ? pk[4 * a + 0] : pk[4 * a + 2];
        unsigned z1 = __shfl_xor(y1, 32);
        unsigned y2 = hi ? pk[4 * a + 1] : pk[4 * a + 3];
        unsigned z2 = __shfl_xor(y2, 32);
        unsigned w0 = hi ? z1 : pk[4 * a + 0];
        unsigned w1 = hi ? z2 : pk[4 * a + 1];
        unsigned w2 = hi ? pk[4 * a + 2] : z1;
        unsigned w3 = hi ? pk[4 * a + 3] : z2;
        uint4v q4 = {w0, w1, w2, w3};
        PA[2 * t + a] = __builtin_bit_cast(bf16x8, q4);
      }
    }
    l_run += lp;

    // ---- O += P @ V: A = P (regs), B = V^T rows d (LDS) ----
    __builtin_amdgcn_s_setprio(1);
#pragma unroll
    for (int dt = 0; dt < 2; dt++)
#pragma unroll
      for (int m = 0; m < 4; m++) {
        const short* vr = &v_s[cur][dt * 32 + ll][((2 * m + hi) ^ l7) * 8];
        o_acc[dt] = mfma32(PA[m], *(const bf16x8*)vr, o_acc[dt]);
      }
    __builtin_amdgcn_s_setprio(0);
    __builtin_amdgcn_s_barrier();  // (b) all waves done reading cur
  }

  // ---- l: lane holds partial for q=ll over its k-half; sum halves ----
  l_run += __shfl_xor(l_run, 32);
  float invl = 1.f / l_run;  // valid for q = ll on all lanes

  // ---- store O (bf16 [B,T1,H*64]); row q via shfl of invl ----
#pragma unroll
  for (int r = 0; r < 16; r++) {
    int q = (r & 3) + 8 * (r >> 2) + 4 * hi;
    float iv = __shfl(invl, q);
    int tg = qb + w * 32 + q;
#pragma unroll
    for (int dt = 0; dt < 2; dt++) {
      Og[(size_t)(b * 2048 + tg) * 1024 + h * 64 + dt * 32 + ll] =
          f2bf(o_acc[dt][r] * iv);
    }
  }
}

// ---------------- launcher ----------------
extern "C" void kernel_launch(void* const* d_in, const int* in_sizes, int n_in,
                              void* d_out, int out_size, void* d_ws, size_t ws_size,
                              hipStream_t stream) {
  const float* x    = (const float*)d_in[0];
  const float* ctx  = (const float*)d_in[1];
  const float* bias = (const float*)d_in[2];
  const float* Wq   = (const float*)d_in[3];
  const float* Wk   = (const float*)d_in[4];
  const float* Wv   = (const float*)d_in[5];
  const float* Wo   = (const float*)d_in[6];
  const float* bo   = (const float*)d_in[7];
  float* out = (float*)d_out;

  char* ws = (char*)d_ws;
  short* x_bf = (short*)(ws + 0);          // 8 MB  (4096x1024 bf16)
  short* c_bf = (short*)(ws + 8388608);    // 8 MB
  short* wq_t = (short*)(ws + 16777216);   // 2 MB  [N][K]
  short* wk_t = (short*)(ws + 18874368);   // 2 MB  (contiguous with wv_t!)
  short* wv_t = (short*)(ws + 20971520);   // 2 MB
  short* wo_t = (short*)(ws + 23068672);   // 2 MB
  short* q_ws = (short*)(ws + 25165824);   // 8 MB  [B,H,T1,64]
  short* k_ws = (short*)(ws + 33554432);   // 8 MB  [B,H,T2,64]
  short* v_ws = (short*)(ws + 41943040);   // 8 MB  [B,H,64,T2]
  short* o_ws = (short*)(ws + 50331648);   // 8 MB  [B,T1,1024]

  cvt_copy<<<1024, 256, 0, stream>>>(x, x_bf, 1048576);
  cvt_copy<<<1024, 256, 0, stream>>>(ctx, c_bf, 1048576);
  dim3 tg(16, 16, 4);
  cvt_transpose4<<<tg, 256, 0, stream>>>(Wq, Wk, Wv, Wo, wq_t, wk_t, wv_t, wo_t);

  dim3 gq(16, 64);  // N=1024
  gemm_bf16<0><<<gq, 256, 0, stream>>>(x_bf, wq_t, q_ws, nullptr, nullptr);
  dim3 gkv(32, 64); // N=2048 merged K|V
  gemm_bf16<3><<<gkv, 256, 0, stream>>>(c_bf, wk_t, k_ws, v_ws, nullptr);

  dim3 fg(16, 16, 2);
  flash_attn<<<fg, 256, 0, stream>>>(q_ws, k_ws, v_ws, bias, o_ws);

  gemm_bf16<2><<<gq, 256, 0, stream>>>(o_ws, wo_t, out, nullptr, bo);
}

// Round 6
// 180.138 us; speedup vs baseline: 1.4722x; 1.4722x over previous
//
#include <hip/hip_runtime.h>

// ---------------- types / helpers ----------------
typedef float  f32x4   __attribute__((ext_vector_type(4)));
typedef float  f32x16  __attribute__((ext_vector_type(16)));
typedef __bf16 bf16x8  __attribute__((ext_vector_type(8)));
typedef __bf16 bf16x2  __attribute__((ext_vector_type(2)));
typedef short  short8v __attribute__((ext_vector_type(8)));
typedef unsigned uint4v __attribute__((ext_vector_type(4)));

__device__ __forceinline__ short f2bf(float f) {
  unsigned u = __float_as_uint(f);
  unsigned r = (u + 0x7FFFu + ((u >> 16) & 1u)) >> 16;  // RNE
  return (short)r;
}

__device__ __forceinline__ f32x4 mfma16(bf16x8 a, bf16x8 b, f32x4 c) {
  return __builtin_amdgcn_mfma_f32_16x16x32_bf16(a, b, c, 0, 0, 0);
}
__device__ __forceinline__ f32x16 mfma32(bf16x8 a, bf16x8 b, f32x16 c) {
  return __builtin_amdgcn_mfma_f32_32x32x16_bf16(a, b, c, 0, 0, 0);
}

// async global->LDS, 16B per lane. lds base must be wave-uniform; HW adds lane*16.
__device__ __forceinline__ void gload16(const void* g, void* l) {
  __builtin_amdgcn_global_load_lds(
      (const __attribute__((address_space(1))) unsigned int*)g,
      (__attribute__((address_space(3))) unsigned int*)l,
      16, 0, 0);
}

// Build PV A-fragment for k-slice pair from packed P dwords via one cross-half
// exchange. pk[i] holds P pairs k_local = 8*(i>>1) + 4*hi + 2*(i&1) + {0,1}.
// PA dword d needs k_local_in_subtile = 16a + 8*hi + 2d: dwords 0,1 from
// hi_src=0's pk[4a+2hi], pk[4a+2hi+1]; dwords 2,3 from hi_src=1's same.
__device__ __forceinline__ bf16x8 p_exchange(const unsigned* pk, int a, int hi) {
  unsigned y1 = hi ? pk[4 * a + 0] : pk[4 * a + 2];
  unsigned z1 = __shfl_xor(y1, 32);
  unsigned y2 = hi ? pk[4 * a + 1] : pk[4 * a + 3];
  unsigned z2 = __shfl_xor(y2, 32);
  unsigned w0 = hi ? z1 : pk[4 * a + 0];
  unsigned w1 = hi ? z2 : pk[4 * a + 1];
  unsigned w2 = hi ? pk[4 * a + 2] : z1;
  unsigned w3 = hi ? pk[4 * a + 3] : z2;
  uint4v q4 = {w0, w1, w2, w3};
  return __builtin_bit_cast(bf16x8, q4);
}

// ---------------- problem constants ----------------
// B=2, T1=T2=2048, D_MODEL=1024, N_HEAD=16, D_HEAD=64

// ---------------- conversion kernels ----------------
__global__ __launch_bounds__(256) void cvt_copy(const float* __restrict__ in,
                                                short* __restrict__ out, int n4) {
  int i = blockIdx.x * blockDim.x + threadIdx.x;
  int stride = gridDim.x * blockDim.x;
  for (; i < n4; i += stride) {
    float4 v = *(const float4*)&in[i * 4];
    short4 o;
    o.x = f2bf(v.x); o.y = f2bf(v.y); o.z = f2bf(v.z); o.w = f2bf(v.w);
    *(short4*)&out[i * 4] = o;
  }
}

// 4 weight matrices [1024][1024] f32 (row=k,col=n) -> bf16 [n][k], one launch.
__global__ __launch_bounds__(256) void cvt_transpose4(const float* __restrict__ W0,
                                                      const float* __restrict__ W1,
                                                      const float* __restrict__ W2,
                                                      const float* __restrict__ W3,
                                                      short* __restrict__ T0,
                                                      short* __restrict__ T1,
                                                      short* __restrict__ T2,
                                                      short* __restrict__ T3) {
  __shared__ short t_s[64][72];
  int z = blockIdx.z;
  const float* W = (z == 0) ? W0 : (z == 1) ? W1 : (z == 2) ? W2 : W3;
  short* Wt = (z == 0) ? T0 : (z == 1) ? T1 : (z == 2) ? T2 : T3;
  int k0 = blockIdx.y * 64, n0 = blockIdx.x * 64;
  int tid = threadIdx.x;
#pragma unroll
  for (int i = 0; i < 4; i++) {
    int idx = i * 256 + tid;
    int r = idx >> 4, cg = idx & 15;
    float4 v = *(const float4*)&W[(k0 + r) * 1024 + n0 + cg * 4];
    t_s[cg * 4 + 0][r] = f2bf(v.x);
    t_s[cg * 4 + 1][r] = f2bf(v.y);
    t_s[cg * 4 + 2][r] = f2bf(v.z);
    t_s[cg * 4 + 3][r] = f2bf(v.w);
  }
  __syncthreads();
#pragma unroll
  for (int i = 0; i < 2; i++) {
    int idx = i * 256 + tid;
    int r = idx >> 3, cg = idx & 7;
    short8v val = *(short8v*)&t_s[r][cg * 8];
    *(short8v*)&Wt[(n0 + r) * 1024 + k0 + cg * 8] = val;
  }
}

// ---------------- GEMM: C[4096][N] = A[4096][1024] @ Bt^T ----------------
// EPI 0: N=1024, bf16 scatter to [B,H,T,64]          (Q projection)
// EPI 2: N=1024, f32 out + b_out                      (final projection)
// EPI 3: N=2048, cols<1024 -> K [B,H,T,64]; cols>=1024 -> V^T [B,H,64,T]
template <int EPI>
__global__ __launch_bounds__(256, 4) void gemm_bf16(const short* __restrict__ A,
                                                    const short* __restrict__ Bt,
                                                    void* __restrict__ out,
                                                    void* __restrict__ out2,
                                                    const float* __restrict__ bout) {
  constexpr int KD = 1024;
  constexpr int NB = (EPI == 3) ? 32 : 16;  // N-tiles
  __shared__ short a_s[64][64];
  __shared__ short b_s[64][64];
  int tid = threadIdx.x, w = tid >> 6, lane = tid & 63;
  int g = lane >> 4, c16 = lane & 15;
  int hsw = c16 & 7;

  // XCD swizzle (bijective: grid % 8 == 0)
  int lin = blockIdx.x + NB * blockIdx.y;
  int wk = (lin & 7) * (NB * 8) + (lin >> 3);
  int c0 = (wk & (NB - 1)) * 64, r0 = (wk / NB) * 64;

  int wr = (w >> 1) * 32, wc = (w & 1) * 32;
  f32x4 acc[2][2] = {};

  for (int kt = 0; kt < KD / 64; ++kt) {
    int k0 = kt * 64;
    __syncthreads();
#pragma unroll
    for (int i = 0; i < 2; i++) {
      int cb = i * 256 + w * 64;
      int c = cb + lane;
      int row = c >> 3, kg = c & 7;
      int sw = (kg ^ (row & 7)) * 8;   // pre-swizzled source col
      gload16(A + (r0 + row) * KD + k0 + sw, (char*)a_s + cb * 16);
      gload16(Bt + (c0 + row) * KD + k0 + sw, (char*)b_s + cb * 16);
    }
    __syncthreads();
#pragma unroll
    for (int kk = 0; kk < 2; kk++) {
      bf16x8 af[2], bf[2];
      int sl0 = ((4 * kk + g) ^ hsw) * 8;
#pragma unroll
      for (int m = 0; m < 2; m++) af[m] = *(const bf16x8*)&a_s[wr + m * 16 + c16][sl0];
#pragma unroll
      for (int n = 0; n < 2; n++) bf[n] = *(const bf16x8*)&b_s[wc + n * 16 + c16][sl0];
#pragma unroll
      for (int m = 0; m < 2; m++)
#pragma unroll
        for (int n = 0; n < 2; n++) acc[m][n] = mfma16(af[m], bf[n], acc[m][n]);
    }
  }

#pragma unroll
  for (int m = 0; m < 2; m++)
#pragma unroll
    for (int n = 0; n < 2; n++)
#pragma unroll
      for (int r = 0; r < 4; r++) {
        int row = r0 + wr + m * 16 + g * 4 + r;  // C/D: row=(lane>>4)*4+reg
        int col = c0 + wc + n * 16 + c16;        //      col=lane&15
        float v = acc[m][n][r];
        int b = row >> 11, t = row & 2047;
        if (EPI == 2) {
          ((float*)out)[row * 1024 + col] = v + bout[col];
        } else if (EPI == 0) {
          int h = col >> 6, d = col & 63;
          ((short*)out)[(((b * 16 + h) * 2048) + t) * 64 + d] = f2bf(v);
        } else {  // EPI 3: merged K | V^T
          if (col < 1024) {
            int h = col >> 6, d = col & 63;
            ((short*)out)[(((b * 16 + h) * 2048) + t) * 64 + d] = f2bf(v);
          } else {
            int cv = col - 1024;
            int h = cv >> 6, d = cv & 63;
            ((short*)out2)[(((b * 16 + h) * 64) + d) * 2048 + t] = f2bf(v);
          }
        }
      }
}

// ---------------- flash attention v5 ----------------
// 4 waves x 32 q-rows (QBLK=128), KVBLK=64, 32x32x16 MFMA, swapped QK^T,
// in-register P. v4 spilled (~150 peak VGPR > 128 cap -> 110MB scratch
// writes); v5 processes one 32-row K-subtile at a time so only ONE f32x16
// sacc and ONE 16-reg bias block are live at once (peak ~110 VGPR).
// K/V double-buffered in 32KB LDS, counted vmcnt, setprio, XCD swizzle.
//
// 32x32 C-layout (m74/m101): col = lane&31, row = (reg&3)+8*(reg>>2)+4*(lane>>5).
// Swapped QK: D[k][q], q = lane&31 -> softmax lane-local, no shuffles.
__global__ __launch_bounds__(256, 4) void flash_attn(const short* __restrict__ Qg,
                                                     const short* __restrict__ Kg,
                                                     const short* __restrict__ Vtg,
                                                     const float* __restrict__ bias,
                                                     short* __restrict__ Og) {
  __shared__ short k_s[2][64][64];   // [buf][k][d]  16B-slot XOR-swizzled by row&7
  __shared__ short v_s[2][64][64];   // [buf][d][k]  16B-slot XOR-swizzled by row&7

  int tid = threadIdx.x, w = tid >> 6, lane = tid & 63;
  int hi = lane >> 5, ll = lane & 31;
  int l7 = ll & 7;

  // XCD swizzle: 512 blocks -> 64-chunks per XCD
  int lin = blockIdx.x + 16 * (blockIdx.y + 16 * blockIdx.z);
  int wk = (lin & 7) * 64 + (lin >> 3);
  int qb = (wk & 15) * 128;
  int h = (wk >> 4) & 15;
  int b = wk >> 8;

  const short* Qh = Qg + (size_t)(b * 16 + h) * 2048 * 64;
  const short* Kh = Kg + (size_t)(b * 16 + h) * 2048 * 64;
  const short* Vh = Vtg + (size_t)(b * 16 + h) * 64 * 2048;

  const float C1 = 0.125f * 1.44269504f;                 // atten_scale * log2(e)
  const float C2 = exp2f(-(float)(h + 1)) * 1.44269504f; // head_scale * log2(e)

  int qrow = qb + w * 32 + ll;
  const float* bp = bias + (size_t)qrow * 2048 + 4 * hi;

  // ---- prologue: stage tile 0 (4 gload16/thread), Q B-frags to registers ----
#pragma unroll
  for (int i = 0; i < 2; i++) {
    int cb = i * 256 + w * 64;
    int c = cb + lane;
    int row = c >> 3, t8 = c & 7, sw = (t8 ^ (row & 7)) * 8;
    gload16(Kh + row * 64 + sw, (char*)&k_s[0][0][0] + cb * 16);
    gload16(Vh + row * 2048 + sw, (char*)&v_s[0][0][0] + cb * 16);
  }
  bf16x8 qf[4];
#pragma unroll
  for (int dm = 0; dm < 4; dm++)
    qf[dm] = *(const bf16x8*)(Qh + (size_t)qrow * 64 + dm * 16 + hi * 8);
  asm volatile("" ::: "memory");  // pin prologue VMEM oldest in the queue

  float l_run = 0.f;
  f32x16 o_acc[2] = {};  // [dt]: col d = dt*32+ll, row q = (r&3)+8*(r>>2)+4*hi

  for (int kt = 0; kt < 32; ++kt) {
    int cur = kt & 1;
    // bias for subtile 0 (k_local 0..31), issued early for latency
    f32x4 bv0[4];
#pragma unroll
    for (int u = 0; u < 4; u++)
      bv0[u] = *(const f32x4*)(bp + kt * 64 + u * 8);

    if (kt < 31) {
      const short* Ks = Kh + (size_t)(kt + 1) * 64 * 64;
      const short* Vs = Vh + (kt + 1) * 64;
#pragma unroll
      for (int i = 0; i < 2; i++) {
        int cb = i * 256 + w * 64;
        int c = cb + lane;
        int row = c >> 3, t8 = c & 7, sw = (t8 ^ (row & 7)) * 8;
        gload16(Ks + row * 64 + sw, (char*)&k_s[cur ^ 1][0][0] + cb * 16);
        gload16(Vs + row * 2048 + sw, (char*)&v_s[cur ^ 1][0][0] + cb * 16);
      }
    }
    // In-order vmcnt retirement: prev iter's consumed bias implies cur-stage
    // complete in steady state; at kt=0 this drains prologue stage+Q exactly.
    asm volatile("s_waitcnt vmcnt(8)" ::: "memory");
    __builtin_amdgcn_s_barrier();  // (a) cur buffer staged on all waves

    // ======== subtile 0 (k rows 0..31) ========
    f32x16 sacc = {};
    __builtin_amdgcn_s_setprio(1);
#pragma unroll
    for (int dm = 0; dm < 4; dm++) {
      const short* kr = &k_s[cur][ll][((2 * dm + hi) ^ l7) * 8];
      sacc = mfma32(*(const bf16x8*)kr, qf[dm], sacc);
    }
    __builtin_amdgcn_s_setprio(0);

    float lp = 0.f;
    unsigned pk[8];
#pragma unroll
    for (int i = 0; i < 8; i++) {
      float p0 = exp2f(sacc[2 * i] * C1 + bv0[i >> 1][2 * (i & 1)] * C2);
      float p1 = exp2f(sacc[2 * i + 1] * C1 + bv0[i >> 1][2 * (i & 1) + 1] * C2);
      lp += p0 + p1;
      bf16x2 pp = {(__bf16)p0, (__bf16)p1};
      pk[i] = __builtin_bit_cast(unsigned, pp);
    }
    l_run += lp;

    // bias for subtile 1 (sacc/bv0 now dead -> low pressure window)
    f32x4 bv1[4];
#pragma unroll
    for (int u = 0; u < 4; u++)
      bv1[u] = *(const f32x4*)(bp + kt * 64 + 32 + u * 8);

    __builtin_amdgcn_s_setprio(1);
#pragma unroll
    for (int a = 0; a < 2; a++) {
      bf16x8 PA = p_exchange(pk, a, hi);
#pragma unroll
      for (int dt = 0; dt < 2; dt++) {  // V k-slice m=a -> slot 2a+hi
        const short* vr = &v_s[cur][dt * 32 + ll][((2 * a + hi) ^ l7) * 8];
        o_acc[dt] = mfma32(PA, *(const bf16x8*)vr, o_acc[dt]);
      }
    }
    __builtin_amdgcn_s_setprio(0);
    asm volatile("" ::: "memory");  // tile boundary: keep subtile-1 ops below

    // ======== subtile 1 (k rows 32..63) ========
    f32x16 sacc1 = {};
    __builtin_amdgcn_s_setprio(1);
#pragma unroll
    for (int dm = 0; dm < 4; dm++) {
      const short* kr = &k_s[cur][32 + ll][((2 * dm + hi) ^ l7) * 8];
      sacc1 = mfma32(*(const bf16x8*)kr, qf[dm], sacc1);
    }
    __builtin_amdgcn_s_setprio(0);

    float lp1 = 0.f;
#pragma unroll
    for (int i = 0; i < 8; i++) {
      float p0 = exp2f(sacc1[2 * i] * C1 + bv1[i >> 1][2 * (i & 1)] * C2);
      float p1 = exp2f(sacc1[2 * i + 1] * C1 + bv1[i >> 1][2 * (i & 1) + 1] * C2);
      lp1 += p0 + p1;
      bf16x2 pp = {(__bf16)p0, (__bf16)p1};
      pk[i] = __builtin_bit_cast(unsigned, pp);
    }
    l_run += lp1;

    __builtin_amdgcn_s_setprio(1);
#pragma unroll
    for (int a = 0; a < 2; a++) {
      bf16x8 PA = p_exchange(pk, a, hi);
#pragma unroll
      for (int dt = 0; dt < 2; dt++) {  // V k-slice m=2+a -> slot 4+2a+hi
        const short* vr = &v_s[cur][dt * 32 + ll][((4 + 2 * a + hi) ^ l7) * 8];
        o_acc[dt] = mfma32(PA, *(const bf16x8*)vr, o_acc[dt]);
      }
    }
    __builtin_amdgcn_s_setprio(0);
    __builtin_amdgcn_s_barrier();  // (b) all waves done reading cur
  }

  // ---- l: lane holds partial for q=ll over its k-subset; sum halves ----
  l_run += __shfl_xor(l_run, 32);
  float invl = 1.f / l_run;  // valid for q = ll on all lanes

  // ---- store O (bf16 [B,T1,H*64]) ----
#pragma unroll
  for (int r = 0; r < 16; r++) {
    int q = (r & 3) + 8 * (r >> 2) + 4 * hi;
    float iv = __shfl(invl, q);
    int tg = qb + w * 32 + q;
#pragma unroll
    for (int dt = 0; dt < 2; dt++) {
      Og[(size_t)(b * 2048 + tg) * 1024 + h * 64 + dt * 32 + ll] =
          f2bf(o_acc[dt][r] * iv);
    }
  }
}

// ---------------- launcher ----------------
extern "C" void kernel_launch(void* const* d_in, const int* in_sizes, int n_in,
                              void* d_out, int out_size, void* d_ws, size_t ws_size,
                              hipStream_t stream) {
  const float* x    = (const float*)d_in[0];
  const float* ctx  = (const float*)d_in[1];
  const float* bias = (const float*)d_in[2];
  const float* Wq   = (const float*)d_in[3];
  const float* Wk   = (const float*)d_in[4];
  const float* Wv   = (const float*)d_in[5];
  const float* Wo   = (const float*)d_in[6];
  const float* bo   = (const float*)d_in[7];
  float* out = (float*)d_out;

  char* ws = (char*)d_ws;
  short* x_bf = (short*)(ws + 0);          // 8 MB  (4096x1024 bf16)
  short* c_bf = (short*)(ws + 8388608);    // 8 MB
  short* wq_t = (short*)(ws + 16777216);   // 2 MB  [N][K]
  short* wk_t = (short*)(ws + 18874368);   // 2 MB  (contiguous with wv_t)
  short* wv_t = (short*)(ws + 20971520);   // 2 MB
  short* wo_t = (short*)(ws + 23068672);   // 2 MB
  short* q_ws = (short*)(ws + 25165824);   // 8 MB  [B,H,T1,64]
  short* k_ws = (short*)(ws + 33554432);   // 8 MB  [B,H,T2,64]
  short* v_ws = (short*)(ws + 41943040);   // 8 MB  [B,H,64,T2]
  short* o_ws = (short*)(ws + 50331648);   // 8 MB  [B,T1,1024]

  cvt_copy<<<1024, 256, 0, stream>>>(x, x_bf, 1048576);
  cvt_copy<<<1024, 256, 0, stream>>>(ctx, c_bf, 1048576);
  dim3 tg(16, 16, 4);
  cvt_transpose4<<<tg, 256, 0, stream>>>(Wq, Wk, Wv, Wo, wq_t, wk_t, wv_t, wo_t);

  dim3 gq(16, 64);  // N=1024
  gemm_bf16<0><<<gq, 256, 0, stream>>>(x_bf, wq_t, q_ws, nullptr, nullptr);
  dim3 gkv(32, 64); // N=2048 merged K|V
  gemm_bf16<3><<<gkv, 256, 0, stream>>>(c_bf, wk_t, k_ws, v_ws, nullptr);

  dim3 fg(16, 16, 2);
  flash_attn<<<fg, 256, 0, stream>>>(q_ws, k_ws, v_ws, bias, o_ws);

  gemm_bf16<2><<<gq, 256, 0, stream>>>(o_ws, wo_t, out, nullptr, bo);
}